// Round 5
// baseline (436.200 us; speedup 1.0000x reference)
//
#include <hip/hip_runtime.h>
#include <hip/hip_bf16.h>
#include <stdint.h>

typedef __bf16 bf16;
typedef __bf16 bf16x4 __attribute__((ext_vector_type(4)));
typedef __bf16 bf16x8 __attribute__((ext_vector_type(8)));
typedef float  f32x4  __attribute__((ext_vector_type(4)));

static constexpr int BB = 128;   // batch
static constexpr int TT = 256;   // time
static constexpr int DD = 768;   // input dim
static constexpr int SS = 128;   // state dim
static constexpr int MM = BB * TT;          // 32768 rows
static constexpr int KW1 = DD + SS;         // 896

// async global->LDS, 16B per lane, wave-uniform LDS base + lane*16
__device__ __forceinline__ void gload16(const void* g, void* l) {
  __builtin_amdgcn_global_load_lds(
      (const __attribute__((address_space(1))) void*)(uintptr_t)g,
      (__attribute__((address_space(3))) void*)(uintptr_t)l, 16, 0, 0);
}

// ---------------------------------------------------------------------------
// k0: weight conversion to bf16. W0 = B_w [128][768]; W1 = [D_w | C_w] [768][896]
// ---------------------------------------------------------------------------
__global__ __launch_bounds__(256) void k0_convert(
    const float* __restrict__ B_w, const float* __restrict__ D_w,
    const float* __restrict__ C_w, bf16* __restrict__ W0, bf16* __restrict__ W1) {
  int i = blockIdx.x * 256 + threadIdx.x;           // grid covers exactly 786432
  if (i < SS * DD) {
    W0[i] = (bf16)B_w[i];
  } else {
    int j = i - SS * DD;
    int n = j / KW1;
    int k = j - n * KW1;
    float v = (k < DD) ? D_w[n * DD + k] : C_w[n * SS + (k - DD)];
    W1[j] = (bf16)v;
  }
}

// ---------------------------------------------------------------------------
// k0x: x (fp32) -> xb (bf16), 8 elems/thread
// ---------------------------------------------------------------------------
__global__ __launch_bounds__(256) void k0x_convert(
    const float* __restrict__ x, bf16* __restrict__ xb) {
  int i = blockIdx.x * 256 + threadIdx.x;   // 12288 blocks = MM*DD/8
  const float4* src = (const float4*)x;
  float4 a = src[i * 2], b = src[i * 2 + 1];
  bf16x8 h;
  h[0] = (bf16)a.x; h[1] = (bf16)a.y; h[2] = (bf16)a.z; h[3] = (bf16)a.w;
  h[4] = (bf16)b.x; h[5] = (bf16)b.y; h[6] = (bf16)b.z; h[7] = (bf16)b.w;
  *(bf16x8*)&xb[i * 8] = h;
}

// ---------------------------------------------------------------------------
// kg<TAG>: bf16 GEMM, m97 structure (verbatim R2 body). mode: 0 = fp32 store,
// 1 = bf16 store, 2 = fp32 accumulate (+=). Runtime branch, epilogue only.
// ---------------------------------------------------------------------------
template <int TAG>
__global__ __launch_bounds__(256) void kg(
    const bf16* __restrict__ A1, const bf16* __restrict__ A2,
    const bf16* __restrict__ W, void* __restrict__ Cv,
    int kt1, int kt2, int lda1, int lda2, int ldb, int ldc, int mode) {
  __shared__ __align__(16) bf16 As[128 * 64];
  __shared__ __align__(16) bf16 Bs[128 * 64];

  const int tid = threadIdx.x;
  const int lane = tid & 63;
  const int wv = tid >> 6;
  const int wr = wv >> 1, wc = wv & 1;
  const int lr = lane & 15, lh = lane >> 4;
  const int bn0 = blockIdx.x * 128;
  const int bm0 = blockIdx.y * 128;

  const int l_row = lane >> 3;        // 0..7 within 8-row chunk
  const int l_col = (lane & 7) * 8;   // elem offset within row

  f32x4 acc[4][4] = {};
  const int KT = kt1 + kt2;

  for (int kt = 0; kt < KT; ++kt) {
    __syncthreads();
    {
      const bf16* Ab; int lda;
      if (kt < kt1) { Ab = A1 + (size_t)bm0 * lda1 + kt * 64; lda = lda1; }
      else          { Ab = A2 + (size_t)bm0 * lda2 + (kt - kt1) * 64; lda = lda2; }
      #pragma unroll
      for (int it = 0; it < 4; ++it) {
        int c = wv * 4 + it;
        gload16(Ab + (size_t)(c * 8 + l_row) * lda + l_col, &As[c * 512]);
      }
    }
    {
      const bf16* Bb = W + (size_t)bn0 * ldb + kt * 64;
      #pragma unroll
      for (int it = 0; it < 4; ++it) {
        int c = wv * 4 + it;
        gload16(Bb + (size_t)(c * 8 + l_row) * ldb + l_col, &Bs[c * 512]);
      }
    }
    __syncthreads();
    #pragma unroll
    for (int kk = 0; kk < 2; ++kk) {
      bf16x8 af[4], bfr[4];
      #pragma unroll
      for (int f = 0; f < 4; ++f)
        af[f] = *(const bf16x8*)&As[(wr * 64 + f * 16 + lr) * 64 + kk * 32 + lh * 8];
      #pragma unroll
      for (int f = 0; f < 4; ++f)
        bfr[f] = *(const bf16x8*)&Bs[(wc * 64 + f * 16 + lr) * 64 + kk * 32 + lh * 8];
      #pragma unroll
      for (int fi = 0; fi < 4; ++fi)
        #pragma unroll
        for (int fj = 0; fj < 4; ++fj)
          acc[fi][fj] = __builtin_amdgcn_mfma_f32_16x16x32_bf16(
              af[fi], bfr[fj], acc[fi][fj], 0, 0, 0);
    }
  }
  // epilogue: C/D layout col = lane&15, row = (lane>>4)*4 + r
  #pragma unroll
  for (int fi = 0; fi < 4; ++fi)
    #pragma unroll
    for (int fj = 0; fj < 4; ++fj) {
      int row = bm0 + wr * 64 + fi * 16 + lh * 4;
      int col = bn0 + wc * 64 + fj * 16 + lr;
      if (mode == 0) {
        float* Cp = (float*)Cv + (size_t)row * ldc + col;
        #pragma unroll
        for (int r = 0; r < 4; ++r) Cp[(size_t)r * ldc] = acc[fi][fj][r];
      } else if (mode == 1) {
        bf16* Cp = (bf16*)Cv + (size_t)row * ldc + col;
        #pragma unroll
        for (int r = 0; r < 4; ++r) Cp[(size_t)r * ldc] = (bf16)acc[fi][fj][r];
      } else {
        float* Cp = (float*)Cv + (size_t)row * ldc + col;
        #pragma unroll
        for (int r = 0; r < 4; ++r) Cp[(size_t)r * ldc] += acc[fi][fj][r];
      }
    }
}

// ---------------------------------------------------------------------------
// k_fused: blocks 0..127 = sequential scan (SB holds Bx bf16 in, states bf16
// out, IN PLACE: global reads of chunk j finish two chunks before writes to
// chunk j). blocks 128..1663 = out = xb @ D_w^T. Both bodies inlined; one
// shared char buffer, plain pointer casts (no unions / struct refs).
// ---------------------------------------------------------------------------
__global__ __launch_bounds__(256) void k_fused(
    const bf16* __restrict__ xb, const bf16* __restrict__ W1,
    float* __restrict__ out, bf16* SB, const float* __restrict__ A) {
  __shared__ __align__(16) char sraw[34304];

  if (blockIdx.x < 128) {
    // ---------------- scan role: 256 threads, 2-way K-split ----------------
    float* st   = (float*)sraw;            // [2][128]  (1024 B)
    float* part = (float*)(sraw + 1024);   // [128]     (512 B)
    float* bxb  = (float*)(sraw + 1536);   // [2][4096] (32768 B)

    const int tid = threadIdx.x;
    const int s = tid & 127;
    const int q = tid >> 7;   // 0 or 1
    bf16* Bxb = SB + (size_t)blockIdx.x * TT * SS;   // in = out (in-place)

    float areg[64];
    {
      const float* Ar = A + s * SS + q * 64;
      #pragma unroll
      for (int j = 0; j < 16; ++j) {
        float4 v = *(const float4*)(Ar + j * 4);
        areg[j * 4 + 0] = v.x; areg[j * 4 + 1] = v.y;
        areg[j * 4 + 2] = v.z; areg[j * 4 + 3] = v.w;
      }
    }
    if (tid < SS) st[tid] = 0.f;

    // chunk = 32 steps * 128 = 4096 bf16; thread covers 16 contiguous elems
    {
      bf16x8 c0 = *(const bf16x8*)(Bxb + tid * 16);
      bf16x8 c1 = *(const bf16x8*)(Bxb + tid * 16 + 8);
      float* d0 = &bxb[tid * 16];
      #pragma unroll
      for (int e = 0; e < 8; ++e) d0[e] = (float)c0[e];
      #pragma unroll
      for (int e = 0; e < 8; ++e) d0[8 + e] = (float)c1[e];
    }
    bf16x8 n0 = *(const bf16x8*)(Bxb + 4096 + tid * 16);
    bf16x8 n1 = *(const bf16x8*)(Bxb + 4096 + tid * 16 + 8);
    __syncthreads();

    int p = 0, cur = 0;
    for (int ch = 0; ch < 8; ++ch) {
      #pragma unroll 1
      for (int t2 = 0; t2 < 32; ++t2) {
        const float* stp = st + p * SS;
        float a0 = 0.f, a1 = 0.f, a2 = 0.f, a3 = 0.f;
        #pragma unroll
        for (int j = 0; j < 64; j += 4) {
          float4 sv = *(const float4*)(stp + (q << 6) + j);   // broadcast
          a0 += areg[j]     * sv.x;
          a1 += areg[j + 1] * sv.y;
          a2 += areg[j + 2] * sv.z;
          a3 += areg[j + 3] * sv.w;
        }
        float partial = (a0 + a1) + (a2 + a3);
        if (q) part[s] = partial;
        __syncthreads();
        if (!q) {
          float tot = partial + part[s] + bxb[cur * 4096 + t2 * SS + s];
          tot = fminf(10.f, fmaxf(-10.f, tot));
          st[(p ^ 1) * SS + s] = tot;
          Bxb[(size_t)(ch * 32 + t2) * SS + s] = (bf16)tot;  // states in place
        }
        __syncthreads();
        p ^= 1;
      }
      if (ch < 7) {
        float* dn = &bxb[(cur ^ 1) * 4096 + tid * 16];
        #pragma unroll
        for (int e = 0; e < 8; ++e) dn[e] = (float)n0[e];
        #pragma unroll
        for (int e = 0; e < 8; ++e) dn[8 + e] = (float)n1[e];
        if (ch < 6) {
          n0 = *(const bf16x8*)(Bxb + (ch + 2) * 4096 + tid * 16);
          n1 = *(const bf16x8*)(Bxb + (ch + 2) * 4096 + tid * 16 + 8);
        }
        __syncthreads();
        cur ^= 1;
      }
    }
  } else {
    // ---------------- GEMM role: out = xb @ D_w^T (verbatim R2 body) -------
    bf16* As = (bf16*)sraw;              // 128*64 bf16 = 16384 B
    bf16* Bs = (bf16*)(sraw + 16384);    // 128*64 bf16 = 16384 B

    const int gb = blockIdx.x - 128;
    const int bn0 = (gb % 6) * 128;
    const int bm0 = (gb / 6) * 128;

    const int tid = threadIdx.x;
    const int lane = tid & 63;
    const int wv = tid >> 6;
    const int wr = wv >> 1, wc = wv & 1;
    const int lr = lane & 15, lh = lane >> 4;
    const int l_row = lane >> 3;
    const int l_col = (lane & 7) * 8;

    f32x4 acc[4][4] = {};

    for (int kt = 0; kt < 12; ++kt) {
      __syncthreads();
      {
        const bf16* Ab = xb + (size_t)bm0 * DD + kt * 64;
        #pragma unroll
        for (int it = 0; it < 4; ++it) {
          int c = wv * 4 + it;
          gload16(Ab + (size_t)(c * 8 + l_row) * DD + l_col, &As[c * 512]);
        }
      }
      {
        const bf16* Bb = W1 + (size_t)bn0 * KW1 + kt * 64;
        #pragma unroll
        for (int it = 0; it < 4; ++it) {
          int c = wv * 4 + it;
          gload16(Bb + (size_t)(c * 8 + l_row) * KW1 + l_col, &Bs[c * 512]);
        }
      }
      __syncthreads();
      #pragma unroll
      for (int kk = 0; kk < 2; ++kk) {
        bf16x8 af[4], bfr[4];
        #pragma unroll
        for (int f = 0; f < 4; ++f)
          af[f] = *(const bf16x8*)&As[(wr * 64 + f * 16 + lr) * 64 + kk * 32 + lh * 8];
        #pragma unroll
        for (int f = 0; f < 4; ++f)
          bfr[f] = *(const bf16x8*)&Bs[(wc * 64 + f * 16 + lr) * 64 + kk * 32 + lh * 8];
        #pragma unroll
        for (int fi = 0; fi < 4; ++fi)
          #pragma unroll
          for (int fj = 0; fj < 4; ++fj)
            acc[fi][fj] = __builtin_amdgcn_mfma_f32_16x16x32_bf16(
                af[fi], bfr[fj], acc[fi][fj], 0, 0, 0);
      }
    }
    #pragma unroll
    for (int fi = 0; fi < 4; ++fi)
      #pragma unroll
      for (int fj = 0; fj < 4; ++fj) {
        int row = bm0 + wr * 64 + fi * 16 + lh * 4;
        int col = bn0 + wc * 64 + fj * 16 + lr;
        float* Cp = out + (size_t)row * DD + col;
        #pragma unroll
        for (int r = 0; r < 4; ++r) Cp[(size_t)r * DD] = acc[fi][fj][r];
      }
  }
}

// ---------------------------------------------------------------------------
// legacy fp32-staging GEMM + 512-thread scan — fallback path only (R1)
// ---------------------------------------------------------------------------
__global__ __launch_bounds__(256) void k_gemm(
    const float* __restrict__ A1, const bf16* __restrict__ A2,
    const bf16* __restrict__ W, float* __restrict__ C,
    int kt1, int kt2, int lda1, int lda2, int ldb, int ldc) {
  __shared__ __align__(16) bf16 As[128][72];
  __shared__ __align__(16) bf16 Bs[128][72];

  const int tid = threadIdx.x;
  const int lane = tid & 63;
  const int wv = tid >> 6;
  const int wr = wv >> 1, wc = wv & 1;
  const int lr = lane & 15, lh = lane >> 4;
  const int bn0 = blockIdx.x * 128;
  const int bm0 = blockIdx.y * 128;

  f32x4 acc[4][4] = {};
  const int KT = kt1 + kt2;

  for (int kt = 0; kt < KT; ++kt) {
    __syncthreads();
    if (kt < kt1) {
      const float* Ab = A1 + (size_t)bm0 * lda1 + kt * 64;
      #pragma unroll
      for (int it = 0; it < 8; ++it) {
        int c = it * 256 + tid;
        int row = c >> 4, col = (c & 15) << 2;
        float4 v = *(const float4*)(Ab + (size_t)row * lda1 + col);
        bf16x4 h;
        h[0] = (bf16)v.x; h[1] = (bf16)v.y; h[2] = (bf16)v.z; h[3] = (bf16)v.w;
        *(bf16x4*)&As[row][col] = h;
      }
    } else {
      const bf16* Ab = A2 + (size_t)bm0 * lda2 + (kt - kt1) * 64;
      #pragma unroll
      for (int it = 0; it < 8; ++it) {
        int c = it * 256 + tid;
        int row = c >> 4, col = (c & 15) << 2;
        bf16x4 v = *(const bf16x4*)(Ab + (size_t)row * lda2 + col);
        *(bf16x4*)&As[row][col] = v;
      }
    }
    {
      const bf16* Bb = W + (size_t)bn0 * ldb + kt * 64;
      #pragma unroll
      for (int it = 0; it < 8; ++it) {
        int c = it * 256 + tid;
        int row = c >> 4, col = (c & 15) << 2;
        bf16x4 v = *(const bf16x4*)(Bb + (size_t)row * ldb + col);
        *(bf16x4*)&Bs[row][col] = v;
      }
    }
    __syncthreads();
    #pragma unroll
    for (int kk = 0; kk < 2; ++kk) {
      bf16x8 af[4], bfr[4];
      #pragma unroll
      for (int f = 0; f < 4; ++f)
        af[f] = *(const bf16x8*)&As[wr * 64 + f * 16 + lr][kk * 32 + lh * 8];
      #pragma unroll
      for (int f = 0; f < 4; ++f)
        bfr[f] = *(const bf16x8*)&Bs[wc * 64 + f * 16 + lr][kk * 32 + lh * 8];
      #pragma unroll
      for (int fi = 0; fi < 4; ++fi)
        #pragma unroll
        for (int fj = 0; fj < 4; ++fj)
          acc[fi][fj] = __builtin_amdgcn_mfma_f32_16x16x32_bf16(
              af[fi], bfr[fj], acc[fi][fj], 0, 0, 0);
    }
  }
  #pragma unroll
  for (int fi = 0; fi < 4; ++fi)
    #pragma unroll
    for (int fj = 0; fj < 4; ++fj) {
      int row = bm0 + wr * 64 + fi * 16 + lh * 4;
      int col = bn0 + wc * 64 + fj * 16 + lr;
      float* Cp = C + (size_t)row * ldc + col;
      #pragma unroll
      for (int r = 0; r < 4; ++r) Cp[(size_t)r * ldc] = acc[fi][fj][r];
    }
}

__global__ __launch_bounds__(512) void k2_scan(
    const float* __restrict__ Bx, const float* __restrict__ A,
    bf16* __restrict__ states) {
  __shared__ __align__(16) float st[2][SS];
  __shared__ __align__(16) float part[3][SS];
  __shared__ __align__(16) float bxb[2][32 * SS];

  const int tid = threadIdx.x;
  const int s = tid & 127;
  const int q = tid >> 7;
  const int b = blockIdx.x;

  float areg[32];
  {
    const float* Ar = A + s * SS + q * 32;
    #pragma unroll
    for (int j = 0; j < 8; ++j) {
      float4 v = *(const float4*)(Ar + j * 4);
      areg[j * 4 + 0] = v.x; areg[j * 4 + 1] = v.y;
      areg[j * 4 + 2] = v.z; areg[j * 4 + 3] = v.w;
    }
  }
  if (tid < SS) st[0][tid] = 0.f;

  const float* Bxb = Bx + (size_t)b * TT * SS;
  {
    float4 c0 = *(const float4*)(Bxb + tid * 4);
    float4 c1 = *(const float4*)(Bxb + 2048 + tid * 4);
    *(float4*)&bxb[0][tid * 4] = c0;
    *(float4*)&bxb[0][2048 + tid * 4] = c1;
  }
  float4 n0 = *(const float4*)(Bxb + 4096 + tid * 4);
  float4 n1 = *(const float4*)(Bxb + 4096 + 2048 + tid * 4);
  __syncthreads();

  bf16* so = states + (size_t)b * TT * SS;
  int p = 0, cur = 0;
  for (int ch = 0; ch < 8; ++ch) {
    #pragma unroll 1
    for (int t2 = 0; t2 < 32; ++t2) {
      const float* stp = st[p];
      float a0 = 0.f, a1 = 0.f, a2 = 0.f, a3 = 0.f;
      #pragma unroll
      for (int j = 0; j < 32; j += 4) {
        float4 sv = *(const float4*)(stp + (q << 5) + j);
        a0 += areg[j]     * sv.x;
        a1 += areg[j + 1] * sv.y;
        a2 += areg[j + 2] * sv.z;
        a3 += areg[j + 3] * sv.w;
      }
      float partial = (a0 + a1) + (a2 + a3);
      if (q) part[q - 1][s] = partial;
      __syncthreads();
      if (q == 0) {
        float tot = partial + part[0][s] + part[1][s] + part[2][s]
                  + bxb[cur][t2 * SS + s];
        tot = fminf(10.f, fmaxf(-10.f, tot));
        st[p ^ 1][s] = tot;
        so[(size_t)(ch * 32 + t2) * SS + s] = (bf16)tot;
      }
      __syncthreads();
      p ^= 1;
    }
    if (ch < 7) {
      *(float4*)&bxb[cur ^ 1][tid * 4] = n0;
      *(float4*)&bxb[cur ^ 1][2048 + tid * 4] = n1;
      if (ch < 6) {
        n0 = *(const float4*)(Bxb + (ch + 2) * 4096 + tid * 4);
        n1 = *(const float4*)(Bxb + (ch + 2) * 4096 + 2048 + tid * 4);
      }
      __syncthreads();
      cur ^= 1;
    }
  }
}

// ---------------------------------------------------------------------------
// k4: per-row gate + residual mix + LayerNorm, in place on d_out.
// ---------------------------------------------------------------------------
__global__ __launch_bounds__(256) void k4_epilogue(
    float* __restrict__ out, const float* __restrict__ x,
    const float* __restrict__ gate_w, const float* __restrict__ gate_b,
    const float* __restrict__ ln_g, const float* __restrict__ ln_b) {
  const int lane = threadIdx.x & 63;
  const int w = threadIdx.x >> 6;
  const int r = blockIdx.x * 4 + w;

  float4* orow = (float4*)(out + (size_t)r * DD);
  const float4* xrow = (const float4*)(x + (size_t)r * DD);
  const float4* g0w = (const float4*)gate_w;
  const float4* g1w = (const float4*)(gate_w + DD);

  float4 o[3], xv[3];
  float d = 0.f;
  #pragma unroll
  for (int i = 0; i < 3; ++i) {
    int c = i * 64 + lane;
    o[i] = orow[c];
    xv[i] = xrow[c];
    float4 w0 = g0w[c], w1 = g1w[c];
    d += xv[i].x * (w0.x - w1.x) + xv[i].y * (w0.y - w1.y)
       + xv[i].z * (w0.z - w1.z) + xv[i].w * (w0.w - w1.w);
  }
  #pragma unroll
  for (int off = 32; off > 0; off >>= 1) d += __shfl_xor(d, off);
  d += gate_b[0] - gate_b[1];
  float g0 = 1.f / (1.f + expf(-d));
  float g1 = 1.f - g0;

  float4 m[3];
  float s1 = 0.f, s2 = 0.f;
  #pragma unroll
  for (int i = 0; i < 3; ++i) {
    m[i].x = g0 * o[i].x + g1 * xv[i].x;
    m[i].y = g0 * o[i].y + g1 * xv[i].y;
    m[i].z = g0 * o[i].z + g1 * xv[i].z;
    m[i].w = g0 * o[i].w + g1 * xv[i].w;
    s1 += (m[i].x + m[i].y) + (m[i].z + m[i].w);
    s2 += (m[i].x * m[i].x + m[i].y * m[i].y)
        + (m[i].z * m[i].z + m[i].w * m[i].w);
  }
  #pragma unroll
  for (int off = 32; off > 0; off >>= 1) {
    s1 += __shfl_xor(s1, off);
    s2 += __shfl_xor(s2, off);
  }
  float mu = s1 * (1.f / 768.f);
  float var = s2 * (1.f / 768.f) - mu * mu;
  float rs = rsqrtf(var + 1e-5f);

  #pragma unroll
  for (int i = 0; i < 3; ++i) {
    int c = i * 64 + lane;
    float4 gg = ((const float4*)ln_g)[c];
    float4 bb = ((const float4*)ln_b)[c];
    float4 y;
    y.x = (m[i].x - mu) * rs * gg.x + bb.x;
    y.y = (m[i].y - mu) * rs * gg.y + bb.y;
    y.z = (m[i].z - mu) * rs * gg.z + bb.z;
    y.w = (m[i].w - mu) * rs * gg.w + bb.w;
    orow[c] = y;
  }
}

// ---------------------------------------------------------------------------
extern "C" void kernel_launch(void* const* d_in, const int* in_sizes, int n_in,
                              void* d_out, int out_size, void* d_ws, size_t ws_size,
                              hipStream_t stream) {
  const float* x   = (const float*)d_in[0];
  const float* A   = (const float*)d_in[1];
  const float* B_w = (const float*)d_in[2];
  const float* C_w = (const float*)d_in[3];
  const float* D_w = (const float*)d_in[4];
  const float* gw  = (const float*)d_in[5];
  const float* gb  = (const float*)d_in[6];
  const float* lng = (const float*)d_in[7];
  const float* lnb = (const float*)d_in[8];
  float* out = (float*)d_out;

  // ws (bf16): W0 | W1 | SB (Bx in -> states out, in place) | xb
  bf16* W0 = (bf16*)d_ws;
  bf16* W1 = W0 + SS * DD;
  bf16* SB = W1 + DD * KW1;
  bf16* xb = SB + (size_t)MM * SS;
  const size_t ws_need_fast =
      2ull * (SS * DD + DD * KW1 + (size_t)MM * SS + (size_t)MM * DD);
  const size_t ws_need_min = 2ull * (SS * DD + DD * KW1 + (size_t)MM * SS);

  k0_convert<<<dim3(3072), dim3(256), 0, stream>>>(B_w, D_w, C_w, W0, W1);

  if (ws_size >= ws_need_fast) {
    k0x_convert<<<dim3(12288), dim3(256), 0, stream>>>(x, xb);
    // SB = Bx (bf16) = xb @ B_w^T
    kg<1><<<dim3(1, 256), dim3(256), 0, stream>>>(
        xb, nullptr, W0, SB, 12, 0, DD, 0, DD, SS, 1);
    // scan (128 blocks, in-place SB) || out = xb @ D_w^T (1536 blocks)
    k_fused<<<dim3(128 + 1536), dim3(256), 0, stream>>>(xb, W1, out, SB, A);
    // out += states @ C_w^T  (K=128: W1 columns 768..895)
    kg<3><<<dim3(6, 256), dim3(256), 0, stream>>>(
        SB, nullptr, W1 + DD, out, 2, 0, SS, 0, KW1, DD, 2);
  } else if (ws_size >= ws_need_min) {
    // fallback (R1 pipeline): fp32 Bx in tail of d_out
    float* Bx = out + ((size_t)MM * DD - (size_t)MM * SS);
    bf16* states = SB;
    k_gemm<<<dim3(1, 256), dim3(256), 0, stream>>>(
        x, nullptr, W0, Bx, 12, 0, DD, 0, DD, SS);
    k2_scan<<<dim3(128), dim3(512), 0, stream>>>(Bx, A, states);
    k_gemm<<<dim3(6, 256), dim3(256), 0, stream>>>(
        x, states, W1, out, 12, 2, DD, SS, KW1, DD);
  }

  k4_epilogue<<<dim3(8192), dim3(256), 0, stream>>>(out, x, gw, gb, lng, lnb);
}

// Round 6
// 411.269 us; speedup vs baseline: 1.0606x; 1.0606x over previous
//
#include <hip/hip_runtime.h>
#include <hip/hip_bf16.h>
#include <stdint.h>

typedef __bf16 bf16;
typedef __bf16 bf16x4 __attribute__((ext_vector_type(4)));
typedef __bf16 bf16x8 __attribute__((ext_vector_type(8)));
typedef float  f32x4  __attribute__((ext_vector_type(4)));

static constexpr int BB = 128;   // batch
static constexpr int TT = 256;   // time
static constexpr int DD = 768;   // input dim
static constexpr int SS = 128;   // state dim
static constexpr int MM = BB * TT;          // 32768 rows
static constexpr int KW1 = DD + SS;         // 896

// async global->LDS, 16B per lane, wave-uniform LDS base + lane*16
__device__ __forceinline__ void gload16(const void* g, void* l) {
  __builtin_amdgcn_global_load_lds(
      (const __attribute__((address_space(1))) void*)(uintptr_t)g,
      (__attribute__((address_space(3))) void*)(uintptr_t)l, 16, 0, 0);
}

// ---------------------------------------------------------------------------
// k0: weight conversion to bf16. W0 = B_w [128][768]; W1 = [D_w | C_w] [768][896]
// ---------------------------------------------------------------------------
__global__ __launch_bounds__(256) void k0_convert(
    const float* __restrict__ B_w, const float* __restrict__ D_w,
    const float* __restrict__ C_w, bf16* __restrict__ W0, bf16* __restrict__ W1) {
  int i = blockIdx.x * 256 + threadIdx.x;           // grid covers exactly 786432
  if (i < SS * DD) {
    W0[i] = (bf16)B_w[i];
  } else {
    int j = i - SS * DD;
    int n = j / KW1;
    int k = j - n * KW1;
    float v = (k < DD) ? D_w[n * DD + k] : C_w[n * SS + (k - DD)];
    W1[j] = (bf16)v;
  }
}

// ---------------------------------------------------------------------------
// k0x_gate: x (fp32) -> xb (bf16) AND gate logit glog[r] = x_r.(gw0-gw1)+gb0-gb1
// One wave per row (4 rows/block), 12 elems/lane.
// ---------------------------------------------------------------------------
__global__ __launch_bounds__(256) void k0x_gate(
    const float* __restrict__ x, bf16* __restrict__ xb,
    const float* __restrict__ gw, const float* __restrict__ gb,
    float* __restrict__ glog) {
  const int lane = threadIdx.x & 63;
  const int wv = threadIdx.x >> 6;
  const int r = blockIdx.x * 4 + wv;     // 0..32767 (grid 8192)
  const float4* xr = (const float4*)(x + (size_t)r * DD);
  const float4* g0w = (const float4*)gw;
  const float4* g1w = (const float4*)(gw + DD);
  float d = 0.f;
  #pragma unroll
  for (int i = 0; i < 3; ++i) {
    int c = i * 64 + lane;
    float4 v = xr[c];
    float4 w0 = g0w[c], w1 = g1w[c];
    d += v.x * (w0.x - w1.x) + v.y * (w0.y - w1.y)
       + v.z * (w0.z - w1.z) + v.w * (w0.w - w1.w);
    bf16x4 h;
    h[0] = (bf16)v.x; h[1] = (bf16)v.y; h[2] = (bf16)v.z; h[3] = (bf16)v.w;
    *(bf16x4*)&xb[(size_t)r * DD + c * 4] = h;
  }
  #pragma unroll
  for (int off = 32; off > 0; off >>= 1) d += __shfl_xor(d, off);
  if (lane == 0) glog[r] = d + gb[0] - gb[1];
}

// ---------------------------------------------------------------------------
// kg<TAG>: bf16 GEMM, m97 structure. mode: 0 = fp32 store, 1 = bf16 store,
// 2 = fp32 accumulate (+=). Runtime branch, epilogue only.
// ---------------------------------------------------------------------------
template <int TAG>
__global__ __launch_bounds__(256) void kg(
    const bf16* __restrict__ A1, const bf16* __restrict__ A2,
    const bf16* __restrict__ W, void* __restrict__ Cv,
    int kt1, int kt2, int lda1, int lda2, int ldb, int ldc, int mode) {
  __shared__ __align__(16) bf16 As[128 * 64];
  __shared__ __align__(16) bf16 Bs[128 * 64];

  const int tid = threadIdx.x;
  const int lane = tid & 63;
  const int wv = tid >> 6;
  const int wr = wv >> 1, wc = wv & 1;
  const int lr = lane & 15, lh = lane >> 4;
  const int bn0 = blockIdx.x * 128;
  const int bm0 = blockIdx.y * 128;

  const int l_row = lane >> 3;        // 0..7 within 8-row chunk
  const int l_col = (lane & 7) * 8;   // elem offset within row

  f32x4 acc[4][4] = {};
  const int KT = kt1 + kt2;

  for (int kt = 0; kt < KT; ++kt) {
    __syncthreads();
    {
      const bf16* Ab; int lda;
      if (kt < kt1) { Ab = A1 + (size_t)bm0 * lda1 + kt * 64; lda = lda1; }
      else          { Ab = A2 + (size_t)bm0 * lda2 + (kt - kt1) * 64; lda = lda2; }
      #pragma unroll
      for (int it = 0; it < 4; ++it) {
        int c = wv * 4 + it;
        gload16(Ab + (size_t)(c * 8 + l_row) * lda + l_col, &As[c * 512]);
      }
    }
    {
      const bf16* Bb = W + (size_t)bn0 * ldb + kt * 64;
      #pragma unroll
      for (int it = 0; it < 4; ++it) {
        int c = wv * 4 + it;
        gload16(Bb + (size_t)(c * 8 + l_row) * ldb + l_col, &Bs[c * 512]);
      }
    }
    __syncthreads();
    #pragma unroll
    for (int kk = 0; kk < 2; ++kk) {
      bf16x8 af[4], bfr[4];
      #pragma unroll
      for (int f = 0; f < 4; ++f)
        af[f] = *(const bf16x8*)&As[(wr * 64 + f * 16 + lr) * 64 + kk * 32 + lh * 8];
      #pragma unroll
      for (int f = 0; f < 4; ++f)
        bfr[f] = *(const bf16x8*)&Bs[(wc * 64 + f * 16 + lr) * 64 + kk * 32 + lh * 8];
      #pragma unroll
      for (int fi = 0; fi < 4; ++fi)
        #pragma unroll
        for (int fj = 0; fj < 4; ++fj)
          acc[fi][fj] = __builtin_amdgcn_mfma_f32_16x16x32_bf16(
              af[fi], bfr[fj], acc[fi][fj], 0, 0, 0);
    }
  }
  #pragma unroll
  for (int fi = 0; fi < 4; ++fi)
    #pragma unroll
    for (int fj = 0; fj < 4; ++fj) {
      int row = bm0 + wr * 64 + fi * 16 + lh * 4;
      int col = bn0 + wc * 64 + fj * 16 + lr;
      if (mode == 0) {
        float* Cp = (float*)Cv + (size_t)row * ldc + col;
        #pragma unroll
        for (int r = 0; r < 4; ++r) Cp[(size_t)r * ldc] = acc[fi][fj][r];
      } else if (mode == 1) {
        bf16* Cp = (bf16*)Cv + (size_t)row * ldc + col;
        #pragma unroll
        for (int r = 0; r < 4; ++r) Cp[(size_t)r * ldc] = (bf16)acc[fi][fj][r];
      } else {
        float* Cp = (float*)Cv + (size_t)row * ldc + col;
        #pragma unroll
        for (int r = 0; r < 4; ++r) Cp[(size_t)r * ldc] += acc[fi][fj][r];
      }
    }
}

// ---------------------------------------------------------------------------
// k_fused: blocks 0..127 = sequential scan AT WAVE PRIORITY 1 (latency-
// critical serial chain must not be starved by co-resident GEMM waves).
// blocks 128..1663 = out = xb @ D_w^T at default priority.
// ---------------------------------------------------------------------------
__global__ __launch_bounds__(256) void k_fused(
    const bf16* __restrict__ xb, const bf16* __restrict__ W1,
    float* __restrict__ out, bf16* SB, const float* __restrict__ A) {
  __shared__ __align__(16) char sraw[34304];

  if (blockIdx.x < 128) {
    __builtin_amdgcn_s_setprio(1);     // T5: favor the serial chain
    float* st   = (float*)sraw;            // [2][128]
    float* part = (float*)(sraw + 1024);   // [128]
    float* bxb  = (float*)(sraw + 1536);   // [2][4096]

    const int tid = threadIdx.x;
    const int s = tid & 127;
    const int q = tid >> 7;   // 0 or 1
    bf16* Bxb = SB + (size_t)blockIdx.x * TT * SS;   // in = out (in-place)

    float areg[64];
    {
      const float* Ar = A + s * SS + q * 64;
      #pragma unroll
      for (int j = 0; j < 16; ++j) {
        float4 v = *(const float4*)(Ar + j * 4);
        areg[j * 4 + 0] = v.x; areg[j * 4 + 1] = v.y;
        areg[j * 4 + 2] = v.z; areg[j * 4 + 3] = v.w;
      }
    }
    if (tid < SS) st[tid] = 0.f;

    {
      bf16x8 c0 = *(const bf16x8*)(Bxb + tid * 16);
      bf16x8 c1 = *(const bf16x8*)(Bxb + tid * 16 + 8);
      float* d0 = &bxb[tid * 16];
      #pragma unroll
      for (int e = 0; e < 8; ++e) d0[e] = (float)c0[e];
      #pragma unroll
      for (int e = 0; e < 8; ++e) d0[8 + e] = (float)c1[e];
    }
    bf16x8 n0 = *(const bf16x8*)(Bxb + 4096 + tid * 16);
    bf16x8 n1 = *(const bf16x8*)(Bxb + 4096 + tid * 16 + 8);
    __syncthreads();

    int p = 0, cur = 0;
    for (int ch = 0; ch < 8; ++ch) {
      #pragma unroll 1
      for (int t2 = 0; t2 < 32; ++t2) {
        const float* stp = st + p * SS;
        float a0 = 0.f, a1 = 0.f, a2 = 0.f, a3 = 0.f;
        #pragma unroll
        for (int j = 0; j < 64; j += 4) {
          float4 sv = *(const float4*)(stp + (q << 6) + j);   // broadcast
          a0 += areg[j]     * sv.x;
          a1 += areg[j + 1] * sv.y;
          a2 += areg[j + 2] * sv.z;
          a3 += areg[j + 3] * sv.w;
        }
        float partial = (a0 + a1) + (a2 + a3);
        if (q) part[s] = partial;
        __syncthreads();
        if (!q) {
          float tot = partial + part[s] + bxb[cur * 4096 + t2 * SS + s];
          tot = fminf(10.f, fmaxf(-10.f, tot));
          st[(p ^ 1) * SS + s] = tot;
          Bxb[(size_t)(ch * 32 + t2) * SS + s] = (bf16)tot;  // states in place
        }
        __syncthreads();
        p ^= 1;
      }
      if (ch < 7) {
        float* dn = &bxb[(cur ^ 1) * 4096 + tid * 16];
        #pragma unroll
        for (int e = 0; e < 8; ++e) dn[e] = (float)n0[e];
        #pragma unroll
        for (int e = 0; e < 8; ++e) dn[8 + e] = (float)n1[e];
        if (ch < 6) {
          n0 = *(const bf16x8*)(Bxb + (ch + 2) * 4096 + tid * 16);
          n1 = *(const bf16x8*)(Bxb + (ch + 2) * 4096 + tid * 16 + 8);
        }
        __syncthreads();
        cur ^= 1;
      }
    }
  } else {
    // ---------------- GEMM role: out = xb @ D_w^T -------------------------
    bf16* As = (bf16*)sraw;              // 128*64 bf16
    bf16* Bs = (bf16*)(sraw + 16384);

    const int gb = blockIdx.x - 128;
    const int bn0 = (gb % 6) * 128;
    const int bm0 = (gb / 6) * 128;

    const int tid = threadIdx.x;
    const int lane = tid & 63;
    const int wv = tid >> 6;
    const int wr = wv >> 1, wc = wv & 1;
    const int lr = lane & 15, lh = lane >> 4;
    const int l_row = lane >> 3;
    const int l_col = (lane & 7) * 8;

    f32x4 acc[4][4] = {};

    for (int kt = 0; kt < 12; ++kt) {
      __syncthreads();
      {
        const bf16* Ab = xb + (size_t)bm0 * DD + kt * 64;
        #pragma unroll
        for (int it = 0; it < 4; ++it) {
          int c = wv * 4 + it;
          gload16(Ab + (size_t)(c * 8 + l_row) * DD + l_col, &As[c * 512]);
        }
      }
      {
        const bf16* Bb = W1 + (size_t)bn0 * KW1 + kt * 64;
        #pragma unroll
        for (int it = 0; it < 4; ++it) {
          int c = wv * 4 + it;
          gload16(Bb + (size_t)(c * 8 + l_row) * KW1 + l_col, &Bs[c * 512]);
        }
      }
      __syncthreads();
      #pragma unroll
      for (int kk = 0; kk < 2; ++kk) {
        bf16x8 af[4], bfr[4];
        #pragma unroll
        for (int f = 0; f < 4; ++f)
          af[f] = *(const bf16x8*)&As[(wr * 64 + f * 16 + lr) * 64 + kk * 32 + lh * 8];
        #pragma unroll
        for (int f = 0; f < 4; ++f)
          bfr[f] = *(const bf16x8*)&Bs[(wc * 64 + f * 16 + lr) * 64 + kk * 32 + lh * 8];
        #pragma unroll
        for (int fi = 0; fi < 4; ++fi)
          #pragma unroll
          for (int fj = 0; fj < 4; ++fj)
            acc[fi][fj] = __builtin_amdgcn_mfma_f32_16x16x32_bf16(
                af[fi], bfr[fj], acc[fi][fj], 0, 0, 0);
      }
    }
    #pragma unroll
    for (int fi = 0; fi < 4; ++fi)
      #pragma unroll
      for (int fj = 0; fj < 4; ++fj) {
        int row = bm0 + wr * 64 + fi * 16 + lh * 4;
        int col = bn0 + wc * 64 + fj * 16 + lr;
        float* Cp = out + (size_t)row * DD + col;
        #pragma unroll
        for (int r = 0; r < 4; ++r) Cp[(size_t)r * DD] = acc[fi][fj][r];
      }
  }
}

// ---------------------------------------------------------------------------
// kT: fused tail. Per block: 16 rows. out_final = LN( g0*(out_xD + states@C_w^T)
// + g1*x ). K=128 MFMA + coalesced epilogue; row stats via shuffle+LDS reduce.
// ---------------------------------------------------------------------------
__global__ __launch_bounds__(256) void kT(
    const bf16* __restrict__ SB, const bf16* __restrict__ Wc,
    float* __restrict__ out, const float* __restrict__ x,
    const float* __restrict__ glog, const float* __restrict__ ln_g,
    const float* __restrict__ ln_b) {
  __shared__ __align__(16) bf16 As[16 * 128];     // states tile
  __shared__ __align__(16) bf16 Ws[128 * 128];    // C_w^T n-subtile
  __shared__ __align__(16) bf16 mbuf[16 * 768];   // mixed values
  __shared__ float wpart[4][16][2];
  __shared__ float mu_s[16], rs_s[16];

  const int tid = threadIdx.x;
  const int lane = tid & 63;
  const int wv = tid >> 6;            // 0..3
  const int lr = lane & 15, lh = lane >> 4;
  const int m0 = blockIdx.x * 16;

  // stage As (16x128 bf16 = 4KB): 1 gload16 per wave (rows 4wv..4wv+3)
  {
    const bf16* g = SB + (size_t)(m0 + wv * 4 + lh) * 128 + lr * 8;
    gload16(g, &As[wv * 512]);
  }

  // per-lane row gates (rows lh*4 + r)
  float g0v[4], g1v[4];
  #pragma unroll
  for (int r = 0; r < 4; ++r) {
    float gl = glog[m0 + lh * 4 + r];
    float g0 = 1.f / (1.f + expf(-gl));
    g0v[r] = g0; g1v[r] = 1.f - g0;
  }

  float s1[4] = {0.f, 0.f, 0.f, 0.f}, s2[4] = {0.f, 0.f, 0.f, 0.f};

  for (int st = 0; st < 6; ++st) {
    const int n0 = st * 128;
    __syncthreads();
    // stage Ws: rows n0..n0+127 of C_w^T (ld 896), 8 chunks/wave
    #pragma unroll
    for (int it = 0; it < 8; ++it) {
      int c = wv * 8 + it;            // chunk = rows 4c..4c+3
      const bf16* g = Wc + (size_t)(n0 + c * 4 + lh) * KW1 + lr * 8;
      gload16(g, &Ws[c * 512]);
    }
    __syncthreads();
    f32x4 acc0 = {0.f, 0.f, 0.f, 0.f}, acc1 = {0.f, 0.f, 0.f, 0.f};
    #pragma unroll
    for (int kk = 0; kk < 4; ++kk) {
      bf16x8 af = *(const bf16x8*)&As[lr * 128 + kk * 32 + lh * 8];
      bf16x8 b0 = *(const bf16x8*)&Ws[((wv * 2 + 0) * 16 + lr) * 128 + kk * 32 + lh * 8];
      bf16x8 b1 = *(const bf16x8*)&Ws[((wv * 2 + 1) * 16 + lr) * 128 + kk * 32 + lh * 8];
      acc0 = __builtin_amdgcn_mfma_f32_16x16x32_bf16(af, b0, acc0, 0, 0, 0);
      acc1 = __builtin_amdgcn_mfma_f32_16x16x32_bf16(af, b1, acc1, 0, 0, 0);
    }
    #pragma unroll
    for (int nn = 0; nn < 2; ++nn) {
      const f32x4 av = nn ? acc1 : acc0;
      int col = n0 + (wv * 2 + nn) * 16 + lr;
      #pragma unroll
      for (int r = 0; r < 4; ++r) {
        int rowl = lh * 4 + r;
        size_t gi = (size_t)(m0 + rowl) * DD + col;
        float raw = av[r] + out[gi];
        float mv = g0v[r] * raw + g1v[r] * x[gi];
        s1[r] += mv; s2[r] += mv * mv;
        mbuf[rowl * DD + col] = (bf16)mv;
      }
    }
  }
  // reduce row stats: over 16 lanes sharing lh, then across 4 waves via LDS
  #pragma unroll
  for (int r = 0; r < 4; ++r) {
    #pragma unroll
    for (int off = 1; off < 16; off <<= 1) {
      s1[r] += __shfl_xor(s1[r], off);
      s2[r] += __shfl_xor(s2[r], off);
    }
  }
  if (lr == 0) {
    #pragma unroll
    for (int r = 0; r < 4; ++r) {
      wpart[wv][lh * 4 + r][0] = s1[r];
      wpart[wv][lh * 4 + r][1] = s2[r];
    }
  }
  __syncthreads();
  if (tid < 16) {
    float S1 = wpart[0][tid][0] + wpart[1][tid][0] + wpart[2][tid][0] + wpart[3][tid][0];
    float S2 = wpart[0][tid][1] + wpart[1][tid][1] + wpart[2][tid][1] + wpart[3][tid][1];
    float mu = S1 * (1.f / 768.f);
    float var = S2 * (1.f / 768.f) - mu * mu;
    mu_s[tid] = mu;
    rs_s[tid] = rsqrtf(fmaxf(var, 0.f) + 1e-5f);
  }
  __syncthreads();
  // coalesced write: 3072 float4 across 256 threads
  #pragma unroll
  for (int i = 0; i < 12; ++i) {
    int gq = i * 256 + tid;
    int row = gq / 192;
    int c4 = gq - row * 192;
    int col = c4 * 4;
    bf16x4 mv = *(const bf16x4*)&mbuf[row * DD + col];
    float4 gg = *(const float4*)&ln_g[col];
    float4 bb = *(const float4*)&ln_b[col];
    float mu = mu_s[row], rs = rs_s[row];
    float4 y;
    y.x = ((float)mv[0] - mu) * rs * gg.x + bb.x;
    y.y = ((float)mv[1] - mu) * rs * gg.y + bb.y;
    y.z = ((float)mv[2] - mu) * rs * gg.z + bb.z;
    y.w = ((float)mv[3] - mu) * rs * gg.w + bb.w;
    *(float4*)&out[(size_t)(m0 + row) * DD + col] = y;
  }
}

// ---------------------------------------------------------------------------
// fallback kernels (R1 pipeline) — only used if ws_size is unexpectedly small
// ---------------------------------------------------------------------------
__global__ __launch_bounds__(256) void k_gemm(
    const float* __restrict__ A1, const bf16* __restrict__ A2,
    const bf16* __restrict__ W, float* __restrict__ C,
    int kt1, int kt2, int lda1, int lda2, int ldb, int ldc) {
  __shared__ __align__(16) bf16 As[128][72];
  __shared__ __align__(16) bf16 Bs[128][72];

  const int tid = threadIdx.x;
  const int lane = tid & 63;
  const int wv = tid >> 6;
  const int wr = wv >> 1, wc = wv & 1;
  const int lr = lane & 15, lh = lane >> 4;
  const int bn0 = blockIdx.x * 128;
  const int bm0 = blockIdx.y * 128;

  f32x4 acc[4][4] = {};
  const int KT = kt1 + kt2;

  for (int kt = 0; kt < KT; ++kt) {
    __syncthreads();
    if (kt < kt1) {
      const float* Ab = A1 + (size_t)bm0 * lda1 + kt * 64;
      #pragma unroll
      for (int it = 0; it < 8; ++it) {
        int c = it * 256 + tid;
        int row = c >> 4, col = (c & 15) << 2;
        float4 v = *(const float4*)(Ab + (size_t)row * lda1 + col);
        bf16x4 h;
        h[0] = (bf16)v.x; h[1] = (bf16)v.y; h[2] = (bf16)v.z; h[3] = (bf16)v.w;
        *(bf16x4*)&As[row][col] = h;
      }
    } else {
      const bf16* Ab = A2 + (size_t)bm0 * lda2 + (kt - kt1) * 64;
      #pragma unroll
      for (int it = 0; it < 8; ++it) {
        int c = it * 256 + tid;
        int row = c >> 4, col = (c & 15) << 2;
        bf16x4 v = *(const bf16x4*)(Ab + (size_t)row * lda2 + col);
        *(bf16x4*)&As[row][col] = v;
      }
    }
    {
      const bf16* Bb = W + (size_t)bn0 * ldb + kt * 64;
      #pragma unroll
      for (int it = 0; it < 8; ++it) {
        int c = it * 256 + tid;
        int row = c >> 4, col = (c & 15) << 2;
        bf16x4 v = *(const bf16x4*)(Bb + (size_t)row * ldb + col);
        *(bf16x4*)&Bs[row][col] = v;
      }
    }
    __syncthreads();
    #pragma unroll
    for (int kk = 0; kk < 2; ++kk) {
      bf16x8 af[4], bfr[4];
      #pragma unroll
      for (int f = 0; f < 4; ++f)
        af[f] = *(const bf16x8*)&As[wr * 64 + f * 16 + lr][kk * 32 + lh * 8];
      #pragma unroll
      for (int f = 0; f < 4; ++f)
        bfr[f] = *(const bf16x8*)&Bs[wc * 64 + f * 16 + lr][kk * 32 + lh * 8];
      #pragma unroll
      for (int fi = 0; fi < 4; ++fi)
        #pragma unroll
        for (int fj = 0; fj < 4; ++fj)
          acc[fi][fj] = __builtin_amdgcn_mfma_f32_16x16x32_bf16(
              af[fi], bfr[fj], acc[fi][fj], 0, 0, 0);
    }
  }
  #pragma unroll
  for (int fi = 0; fi < 4; ++fi)
    #pragma unroll
    for (int fj = 0; fj < 4; ++fj) {
      int row = bm0 + wr * 64 + fi * 16 + lh * 4;
      int col = bn0 + wc * 64 + fj * 16 + lr;
      float* Cp = C + (size_t)row * ldc + col;
      #pragma unroll
      for (int r = 0; r < 4; ++r) Cp[(size_t)r * ldc] = acc[fi][fj][r];
    }
}

__global__ __launch_bounds__(512) void k2_scan(
    const float* __restrict__ Bx, const float* __restrict__ A,
    bf16* __restrict__ states) {
  __shared__ __align__(16) float st[2][SS];
  __shared__ __align__(16) float part[3][SS];
  __shared__ __align__(16) float bxb[2][32 * SS];

  const int tid = threadIdx.x;
  const int s = tid & 127;
  const int q = tid >> 7;
  const int b = blockIdx.x;

  float areg[32];
  {
    const float* Ar = A + s * SS + q * 32;
    #pragma unroll
    for (int j = 0; j < 8; ++j) {
      float4 v = *(const float4*)(Ar + j * 4);
      areg[j * 4 + 0] = v.x; areg[j * 4 + 1] = v.y;
      areg[j * 4 + 2] = v.z; areg[j * 4 + 3] = v.w;
    }
  }
  if (tid < SS) st[0][tid] = 0.f;

  const float* Bxb = Bx + (size_t)b * TT * SS;
  {
    float4 c0 = *(const float4*)(Bxb + tid * 4);
    float4 c1 = *(const float4*)(Bxb + 2048 + tid * 4);
    *(float4*)&bxb[0][tid * 4] = c0;
    *(float4*)&bxb[0][2048 + tid * 4] = c1;
  }
  float4 n0 = *(const float4*)(Bxb + 4096 + tid * 4);
  float4 n1 = *(const float4*)(Bxb + 4096 + 2048 + tid * 4);
  __syncthreads();

  bf16* so = states + (size_t)b * TT * SS;
  int p = 0, cur = 0;
  for (int ch = 0; ch < 8; ++ch) {
    #pragma unroll 1
    for (int t2 = 0; t2 < 32; ++t2) {
      const float* stp = st[p];
      float a0 = 0.f, a1 = 0.f, a2 = 0.f, a3 = 0.f;
      #pragma unroll
      for (int j = 0; j < 32; j += 4) {
        float4 sv = *(const float4*)(stp + (q << 5) + j);
        a0 += areg[j]     * sv.x;
        a1 += areg[j + 1] * sv.y;
        a2 += areg[j + 2] * sv.z;
        a3 += areg[j + 3] * sv.w;
      }
      float partial = (a0 + a1) + (a2 + a3);
      if (q) part[q - 1][s] = partial;
      __syncthreads();
      if (q == 0) {
        float tot = partial + part[0][s] + part[1][s] + part[2][s]
                  + bxb[cur][t2 * SS + s];
        tot = fminf(10.f, fmaxf(-10.f, tot));
        st[p ^ 1][s] = tot;
        so[(size_t)(ch * 32 + t2) * SS + s] = (bf16)tot;
      }
      __syncthreads();
      p ^= 1;
    }
    if (ch < 7) {
      *(float4*)&bxb[cur ^ 1][tid * 4] = n0;
      *(float4*)&bxb[cur ^ 1][2048 + tid * 4] = n1;
      if (ch < 6) {
        n0 = *(const float4*)(Bxb + (ch + 2) * 4096 + tid * 4);
        n1 = *(const float4*)(Bxb + (ch + 2) * 4096 + 2048 + tid * 4);
      }
      __syncthreads();
      cur ^= 1;
    }
  }
}

__global__ __launch_bounds__(256) void k4_epilogue(
    float* __restrict__ out, const float* __restrict__ x,
    const float* __restrict__ gate_w, const float* __restrict__ gate_b,
    const float* __restrict__ ln_g, const float* __restrict__ ln_b) {
  const int lane = threadIdx.x & 63;
  const int w = threadIdx.x >> 6;
  const int r = blockIdx.x * 4 + w;

  float4* orow = (float4*)(out + (size_t)r * DD);
  const float4* xrow = (const float4*)(x + (size_t)r * DD);
  const float4* g0w = (const float4*)gate_w;
  const float4* g1w = (const float4*)(gate_w + DD);

  float4 o[3], xv[3];
  float d = 0.f;
  #pragma unroll
  for (int i = 0; i < 3; ++i) {
    int c = i * 64 + lane;
    o[i] = orow[c];
    xv[i] = xrow[c];
    float4 w0 = g0w[c], w1 = g1w[c];
    d += xv[i].x * (w0.x - w1.x) + xv[i].y * (w0.y - w1.y)
       + xv[i].z * (w0.z - w1.z) + xv[i].w * (w0.w - w1.w);
  }
  #pragma unroll
  for (int off = 32; off > 0; off >>= 1) d += __shfl_xor(d, off);
  d += gate_b[0] - gate_b[1];
  float g0 = 1.f / (1.f + expf(-d));
  float g1 = 1.f - g0;

  float4 m[3];
  float s1 = 0.f, s2 = 0.f;
  #pragma unroll
  for (int i = 0; i < 3; ++i) {
    m[i].x = g0 * o[i].x + g1 * xv[i].x;
    m[i].y = g0 * o[i].y + g1 * xv[i].y;
    m[i].z = g0 * o[i].z + g1 * xv[i].z;
    m[i].w = g0 * o[i].w + g1 * xv[i].w;
    s1 += (m[i].x + m[i].y) + (m[i].z + m[i].w);
    s2 += (m[i].x * m[i].x + m[i].y * m[i].y)
        + (m[i].z * m[i].z + m[i].w * m[i].w);
  }
  #pragma unroll
  for (int off = 32; off > 0; off >>= 1) {
    s1 += __shfl_xor(s1, off);
    s2 += __shfl_xor(s2, off);
  }
  float mu = s1 * (1.f / 768.f);
  float var = s2 * (1.f / 768.f) - mu * mu;
  float rs = rsqrtf(var + 1e-5f);

  #pragma unroll
  for (int i = 0; i < 3; ++i) {
    int c = i * 64 + lane;
    float4 gg = ((const float4*)ln_g)[c];
    float4 bb = ((const float4*)ln_b)[c];
    float4 y;
    y.x = (m[i].x - mu) * rs * gg.x + bb.x;
    y.y = (m[i].y - mu) * rs * gg.y + bb.y;
    y.z = (m[i].z - mu) * rs * gg.z + bb.z;
    y.w = (m[i].w - mu) * rs * gg.w + bb.w;
    orow[c] = y;
  }
}

// ---------------------------------------------------------------------------
extern "C" void kernel_launch(void* const* d_in, const int* in_sizes, int n_in,
                              void* d_out, int out_size, void* d_ws, size_t ws_size,
                              hipStream_t stream) {
  const float* x   = (const float*)d_in[0];
  const float* A   = (const float*)d_in[1];
  const float* B_w = (const float*)d_in[2];
  const float* C_w = (const float*)d_in[3];
  const float* D_w = (const float*)d_in[4];
  const float* gw  = (const float*)d_in[5];
  const float* gb  = (const float*)d_in[6];
  const float* lng = (const float*)d_in[7];
  const float* lnb = (const float*)d_in[8];
  float* out = (float*)d_out;

  // ws: W0 | W1 | SB (Bx -> states, in place) | xb | glog(fp32)
  bf16* W0 = (bf16*)d_ws;
  bf16* W1 = W0 + SS * DD;
  bf16* SB = W1 + DD * KW1;
  bf16* xb = SB + (size_t)MM * SS;
  float* glog = (float*)(xb + (size_t)MM * DD);
  const size_t base_bf16 =
      2ull * (SS * DD + DD * KW1 + (size_t)MM * SS + (size_t)MM * DD);
  const size_t ws_need_full = base_bf16 + 4ull * MM;
  const size_t ws_need_min = 2ull * (SS * DD + DD * KW1 + (size_t)MM * SS);

  k0_convert<<<dim3(3072), dim3(256), 0, stream>>>(B_w, D_w, C_w, W0, W1);

  if (ws_size >= ws_need_full) {
    // xb + gate logits in one pass
    k0x_gate<<<dim3(8192), dim3(256), 0, stream>>>(x, xb, gw, gb, glog);
    // SB = Bx (bf16) = xb @ B_w^T
    kg<1><<<dim3(1, 256), dim3(256), 0, stream>>>(
        xb, nullptr, W0, SB, 12, 0, DD, 0, DD, SS, 1);
    // scan (prio-1, in-place SB) || out = xb @ D_w^T
    k_fused<<<dim3(128 + 1536), dim3(256), 0, stream>>>(xb, W1, out, SB, A);
    // fused tail: out = LN(g0*(out + states@C_w^T) + g1*x)
    kT<<<dim3(2048), dim3(256), 0, stream>>>(
        SB, W1 + DD, out, x, glog, lng, lnb);
  } else if (ws_size >= ws_need_min) {
    // fallback (R1 pipeline): fp32 Bx in tail of d_out
    float* Bx = out + ((size_t)MM * DD - (size_t)MM * SS);
    bf16* states = SB;
    k_gemm<<<dim3(1, 256), dim3(256), 0, stream>>>(
        x, nullptr, W0, Bx, 12, 0, DD, 0, DD, SS);
    k2_scan<<<dim3(128), dim3(512), 0, stream>>>(Bx, A, states);
    k_gemm<<<dim3(6, 256), dim3(256), 0, stream>>>(
        x, states, W1, out, 12, 2, DD, SS, KW1, DD);
    k4_epilogue<<<dim3(8192), dim3(256), 0, stream>>>(out, x, gw, gb, lng, lnb);
  }
}

// Round 8
// 358.791 us; speedup vs baseline: 1.2157x; 1.1463x over previous
//
#include <hip/hip_runtime.h>
#include <hip/hip_bf16.h>
#include <stdint.h>

typedef __bf16 bf16;
typedef __bf16 bf16x4 __attribute__((ext_vector_type(4)));
typedef __bf16 bf16x8 __attribute__((ext_vector_type(8)));
typedef float  f32x4  __attribute__((ext_vector_type(4)));

static constexpr int BB = 128;   // batch
static constexpr int TT = 256;   // time
static constexpr int DD = 768;   // input dim
static constexpr int SS = 128;   // state dim
static constexpr int MM = BB * TT;          // 32768 rows
static constexpr int KW1 = DD + SS;         // 896

// async global->LDS, 16B per lane, wave-uniform LDS base + lane*16
__device__ __forceinline__ void gload16(const void* g, void* l) {
  __builtin_amdgcn_global_load_lds(
      (const __attribute__((address_space(1))) void*)(uintptr_t)g,
      (__attribute__((address_space(3))) void*)(uintptr_t)l, 16, 0, 0);
}

// ---------------------------------------------------------------------------
// k0: weight conversion to bf16. W0 = B_w [128][768]; W1 = [D_w | C_w] [768][896]
// ---------------------------------------------------------------------------
__global__ __launch_bounds__(256) void k0_convert(
    const float* __restrict__ B_w, const float* __restrict__ D_w,
    const float* __restrict__ C_w, bf16* __restrict__ W0, bf16* __restrict__ W1) {
  int i = blockIdx.x * 256 + threadIdx.x;           // grid covers exactly 786432
  if (i < SS * DD) {
    W0[i] = (bf16)B_w[i];
  } else {
    int j = i - SS * DD;
    int n = j / KW1;
    int k = j - n * KW1;
    float v = (k < DD) ? D_w[n * DD + k] : C_w[n * SS + (k - DD)];
    W1[j] = (bf16)v;
  }
}

// ---------------------------------------------------------------------------
// k0x_gate: x (fp32) -> xb (bf16) AND gate logit glog[r]
// ---------------------------------------------------------------------------
__global__ __launch_bounds__(256) void k0x_gate(
    const float* __restrict__ x, bf16* __restrict__ xb,
    const float* __restrict__ gw, const float* __restrict__ gb,
    float* __restrict__ glog) {
  const int lane = threadIdx.x & 63;
  const int wv = threadIdx.x >> 6;
  const int r = blockIdx.x * 4 + wv;     // grid 8192
  const float4* xr = (const float4*)(x + (size_t)r * DD);
  const float4* g0w = (const float4*)gw;
  const float4* g1w = (const float4*)(gw + DD);
  float d = 0.f;
  #pragma unroll
  for (int i = 0; i < 3; ++i) {
    int c = i * 64 + lane;
    float4 v = xr[c];
    float4 w0 = g0w[c], w1 = g1w[c];
    d += v.x * (w0.x - w1.x) + v.y * (w0.y - w1.y)
       + v.z * (w0.z - w1.z) + v.w * (w0.w - w1.w);
    bf16x4 h;
    h[0] = (bf16)v.x; h[1] = (bf16)v.y; h[2] = (bf16)v.z; h[3] = (bf16)v.w;
    *(bf16x4*)&xb[(size_t)r * DD + c * 4] = h;
  }
  #pragma unroll
  for (int off = 32; off > 0; off >>= 1) d += __shfl_xor(d, off);
  if (lane == 0) glog[r] = d + gb[0] - gb[1];
}

// ---------------------------------------------------------------------------
// kg<TAG>: 4-wave 128x128 GEMM, swizzled LDS (linear dest, pre-swizzled global
// source col ^= (row&7)*8 elems; same XOR on read). mode: 0 fp32, 1 bf16, 2 +=.
// ---------------------------------------------------------------------------
template <int TAG>
__global__ __launch_bounds__(256) void kg(
    const bf16* __restrict__ A1, const bf16* __restrict__ A2,
    const bf16* __restrict__ W, void* __restrict__ Cv,
    int kt1, int kt2, int lda1, int lda2, int ldb, int ldc, int mode) {
  __shared__ __align__(16) bf16 As[128 * 64];
  __shared__ __align__(16) bf16 Bs[128 * 64];

  const int tid = threadIdx.x;
  const int lane = tid & 63;
  const int wv = tid >> 6;
  const int wr = wv >> 1, wc = wv & 1;
  const int lr = lane & 15, lh = lane >> 4;
  const int bn0 = blockIdx.x * 128;
  const int bm0 = blockIdx.y * 128;

  const int l_row = lane >> 3;                       // 0..7 within 8-row chunk
  const int l_col = ((lane & 7) ^ l_row) * 8;        // inverse-swizzled source

  f32x4 acc[4][4] = {};
  const int KT = kt1 + kt2;

  for (int kt = 0; kt < KT; ++kt) {
    __syncthreads();
    {
      const bf16* Ab; int lda;
      if (kt < kt1) { Ab = A1 + (size_t)bm0 * lda1 + kt * 64; lda = lda1; }
      else          { Ab = A2 + (size_t)bm0 * lda2 + (kt - kt1) * 64; lda = lda2; }
      #pragma unroll
      for (int it = 0; it < 4; ++it) {
        int c = wv * 4 + it;
        gload16(Ab + (size_t)(c * 8 + l_row) * lda + l_col, &As[c * 512]);
      }
    }
    {
      const bf16* Bb = W + (size_t)bn0 * ldb + kt * 64;
      #pragma unroll
      for (int it = 0; it < 4; ++it) {
        int c = wv * 4 + it;
        gload16(Bb + (size_t)(c * 8 + l_row) * ldb + l_col, &Bs[c * 512]);
      }
    }
    __syncthreads();
    #pragma unroll
    for (int kk = 0; kk < 2; ++kk) {
      const int ec = (kk * 32 + lh * 8) ^ ((lr & 7) * 8);   // swizzled read col
      bf16x8 af[4], bfr[4];
      #pragma unroll
      for (int f = 0; f < 4; ++f)
        af[f] = *(const bf16x8*)&As[(wr * 64 + f * 16 + lr) * 64 + ec];
      #pragma unroll
      for (int f = 0; f < 4; ++f)
        bfr[f] = *(const bf16x8*)&Bs[(wc * 64 + f * 16 + lr) * 64 + ec];
      #pragma unroll
      for (int fi = 0; fi < 4; ++fi)
        #pragma unroll
        for (int fj = 0; fj < 4; ++fj)
          acc[fi][fj] = __builtin_amdgcn_mfma_f32_16x16x32_bf16(
              af[fi], bfr[fj], acc[fi][fj], 0, 0, 0);
    }
  }
  #pragma unroll
  for (int fi = 0; fi < 4; ++fi)
    #pragma unroll
    for (int fj = 0; fj < 4; ++fj) {
      int row = bm0 + wr * 64 + fi * 16 + lh * 4;
      int col = bn0 + wc * 64 + fj * 16 + lr;
      if (mode == 0) {
        float* Cp = (float*)Cv + (size_t)row * ldc + col;
        #pragma unroll
        for (int r = 0; r < 4; ++r) Cp[(size_t)r * ldc] = acc[fi][fj][r];
      } else if (mode == 1) {
        bf16* Cp = (bf16*)Cv + (size_t)row * ldc + col;
        #pragma unroll
        for (int r = 0; r < 4; ++r) Cp[(size_t)r * ldc] = (bf16)acc[fi][fj][r];
      } else {
        float* Cp = (float*)Cv + (size_t)row * ldc + col;
        #pragma unroll
        for (int r = 0; r < 4; ++r) Cp[(size_t)r * ldc] += acc[fi][fj][r];
      }
    }
}

// ---------------------------------------------------------------------------
// k_fused (512 threads): blocks 0..127 = scan, 4-way K-split (proven 88us
// structure), bf16 LDS chunk buffer, states written in place over Bx.
// blocks 128..895 = out = xb @ D_w^T, 8 waves, 128x256 tile, swizzled LDS.
// ---------------------------------------------------------------------------
__global__ __launch_bounds__(512) void k_fused(
    const bf16* __restrict__ xb, const bf16* __restrict__ W1,
    float* __restrict__ out, bf16* SB, const float* __restrict__ A) {
  __shared__ __align__(16) char sraw[49152];

  if (blockIdx.x < 128) {
    __builtin_amdgcn_s_setprio(1);     // favor the serial chain
    float* st   = (float*)sraw;              // [2][128]   1 KB
    float* part = (float*)(sraw + 1024);     // [3][128]   1.5 KB
    bf16* bxbB  = (bf16*)(sraw + 2560);      // [2][4096]  16 KB

    const int tid = threadIdx.x;
    const int s = tid & 127;
    const int q = tid >> 7;          // 0..3 K-split
    bf16* Bxb = SB + (size_t)blockIdx.x * TT * SS;   // in = out (in-place)

    float areg[32];
    {
      const float* Ar = A + s * SS + q * 32;
      #pragma unroll
      for (int j = 0; j < 8; ++j) {
        float4 v = *(const float4*)(Ar + j * 4);
        areg[j * 4 + 0] = v.x; areg[j * 4 + 1] = v.y;
        areg[j * 4 + 2] = v.z; areg[j * 4 + 3] = v.w;
      }
    }
    if (tid < SS) st[tid] = 0.f;

    // chunk = 32 steps * 128 = 4096 bf16 = 8KB; one bf16x8 per thread
    *(bf16x8*)&bxbB[tid * 8] = *(const bf16x8*)(Bxb + tid * 8);
    bf16x8 nx = *(const bf16x8*)(Bxb + 4096 + tid * 8);
    __syncthreads();

    int p = 0, cur = 0;
    for (int ch = 0; ch < 8; ++ch) {
      #pragma unroll 1
      for (int t2 = 0; t2 < 32; ++t2) {
        const float* stp = st + p * SS;
        float a0 = 0.f, a1 = 0.f, a2 = 0.f, a3 = 0.f;
        #pragma unroll
        for (int j = 0; j < 32; j += 4) {
          float4 sv = *(const float4*)(stp + (q << 5) + j);   // broadcast
          a0 += areg[j]     * sv.x;
          a1 += areg[j + 1] * sv.y;
          a2 += areg[j + 2] * sv.z;
          a3 += areg[j + 3] * sv.w;
        }
        float partial = (a0 + a1) + (a2 + a3);
        if (q) part[(q - 1) * SS + s] = partial;
        __syncthreads();
        if (q == 0) {
          float tot = partial + part[s] + part[SS + s] + part[2 * SS + s]
                    + (float)bxbB[cur * 4096 + t2 * SS + s];
          tot = fminf(10.f, fmaxf(-10.f, tot));
          st[(p ^ 1) * SS + s] = tot;
          Bxb[(size_t)(ch * 32 + t2) * SS + s] = (bf16)tot;   // states in place
        }
        __syncthreads();
        p ^= 1;
      }
      if (ch < 7) {
        *(bf16x8*)&bxbB[(cur ^ 1) * 4096 + tid * 8] = nx;
        if (ch < 6) nx = *(const bf16x8*)(Bxb + (ch + 2) * 4096 + tid * 8);
        __syncthreads();
        cur ^= 1;
      }
    }
  } else {
    // -------- GEMM role: 8 waves, 128(M) x 256(N) tile, BK=64 --------------
    bf16* As = (bf16*)sraw;              // 128*64 bf16 = 16 KB
    bf16* Bs = (bf16*)(sraw + 16384);    // 256*64 bf16 = 32 KB

    const int gb = blockIdx.x - 128;     // 0..767
    const int bm0 = (gb / 3) * 128;
    const int bn0 = (gb % 3) * 256;

    const int tid = threadIdx.x;
    const int lane = tid & 63;
    const int wv = tid >> 6;             // 0..7
    const int wr = wv >> 2, wc = wv & 3; // M-half, N-quarter
    const int lr = lane & 15, lh = lane >> 4;
    const int l_row = lane >> 3;
    const int l_col = ((lane & 7) ^ l_row) * 8;    // inverse-swizzled source

    f32x4 acc[4][4] = {};

    for (int kt = 0; kt < 12; ++kt) {
      __syncthreads();
      {
        const bf16* Ab = xb + (size_t)bm0 * DD + kt * 64;
        #pragma unroll
        for (int it = 0; it < 2; ++it) {
          int c = wv * 2 + it;           // 0..15
          gload16(Ab + (size_t)(c * 8 + l_row) * DD + l_col, &As[c * 512]);
        }
      }
      {
        const bf16* Bb = W1 + (size_t)bn0 * KW1 + kt * 64;
        #pragma unroll
        for (int it = 0; it < 4; ++it) {
          int c = wv * 4 + it;           // 0..31
          gload16(Bb + (size_t)(c * 8 + l_row) * KW1 + l_col, &Bs[c * 512]);
        }
      }
      __syncthreads();
      #pragma unroll
      for (int kk = 0; kk < 2; ++kk) {
        const int ec = (kk * 32 + lh * 8) ^ ((lr & 7) * 8);
        bf16x8 af[4], bfr[4];
        #pragma unroll
        for (int f = 0; f < 4; ++f)
          af[f] = *(const bf16x8*)&As[(wr * 64 + f * 16 + lr) * 64 + ec];
        #pragma unroll
        for (int f = 0; f < 4; ++f)
          bfr[f] = *(const bf16x8*)&Bs[(wc * 64 + f * 16 + lr) * 64 + ec];
        #pragma unroll
        for (int fi = 0; fi < 4; ++fi)
          #pragma unroll
          for (int fj = 0; fj < 4; ++fj)
            acc[fi][fj] = __builtin_amdgcn_mfma_f32_16x16x32_bf16(
                af[fi], bfr[fj], acc[fi][fj], 0, 0, 0);
      }
    }
    #pragma unroll
    for (int fi = 0; fi < 4; ++fi)
      #pragma unroll
      for (int fj = 0; fj < 4; ++fj) {
        int row = bm0 + wr * 64 + fi * 16 + lh * 4;
        int col = bn0 + wc * 64 + fj * 16 + lr;
        float* Cp = out + (size_t)row * DD + col;
        #pragma unroll
        for (int r = 0; r < 4; ++r) Cp[(size_t)r * DD] = acc[fi][fj][r];
      }
  }
}

// ---------------------------------------------------------------------------
// kT: fused tail. Per block 16 rows: out = LN(g0*(out_xD + states@C_w^T)+g1*x)
// Swizzled As/Ws LDS tiles.
// ---------------------------------------------------------------------------
__global__ __launch_bounds__(256) void kT(
    const bf16* __restrict__ SB, const bf16* __restrict__ Wc,
    float* __restrict__ out, const float* __restrict__ x,
    const float* __restrict__ glog, const float* __restrict__ ln_g,
    const float* __restrict__ ln_b) {
  __shared__ __align__(16) bf16 As[16 * 128];     // states tile
  __shared__ __align__(16) bf16 Ws[128 * 128];    // C_w^T n-subtile
  __shared__ __align__(16) bf16 mbuf[16 * 768];   // mixed values
  __shared__ float wpart[4][16][2];
  __shared__ float mu_s[16], rs_s[16];

  const int tid = threadIdx.x;
  const int lane = tid & 63;
  const int wv = tid >> 6;            // 0..3
  const int lr = lane & 15, lh = lane >> 4;
  const int m0 = blockIdx.x * 16;

  // stage As (16x128): wave wv covers rows wv*4+lh; source col swizzled
  {
    const int r7 = (wv * 4 + lh) & 7;
    const bf16* g = SB + (size_t)(m0 + wv * 4 + lh) * 128 + ((lr ^ r7) * 8);
    gload16(g, &As[wv * 512]);
  }

  float g0v[4], g1v[4];
  #pragma unroll
  for (int r = 0; r < 4; ++r) {
    float gl = glog[m0 + lh * 4 + r];
    float g0 = 1.f / (1.f + expf(-gl));
    g0v[r] = g0; g1v[r] = 1.f - g0;
  }

  float s1[4] = {0.f, 0.f, 0.f, 0.f}, s2[4] = {0.f, 0.f, 0.f, 0.f};

  for (int st = 0; st < 6; ++st) {
    const int n0 = st * 128;
    __syncthreads();
    #pragma unroll
    for (int it = 0; it < 8; ++it) {
      int c = wv * 8 + it;            // chunk = 4 rows
      const int r7 = (c * 4 + lh) & 7;
      const bf16* g = Wc + (size_t)(n0 + c * 4 + lh) * KW1 + ((lr ^ r7) * 8);
      gload16(g, &Ws[c * 512]);
    }
    __syncthreads();
    f32x4 acc0 = {0.f, 0.f, 0.f, 0.f}, acc1 = {0.f, 0.f, 0.f, 0.f};
    #pragma unroll
    for (int kk = 0; kk < 4; ++kk) {
      const int ec = (kk * 32 + lh * 8) ^ ((lr & 7) * 8);
      bf16x8 af = *(const bf16x8*)&As[lr * 128 + ec];
      bf16x8 b0 = *(const bf16x8*)&Ws[((wv * 2 + 0) * 16 + lr) * 128 + ec];
      bf16x8 b1 = *(const bf16x8*)&Ws[((wv * 2 + 1) * 16 + lr) * 128 + ec];
      acc0 = __builtin_amdgcn_mfma_f32_16x16x32_bf16(af, b0, acc0, 0, 0, 0);
      acc1 = __builtin_amdgcn_mfma_f32_16x16x32_bf16(af, b1, acc1, 0, 0, 0);
    }
    #pragma unroll
    for (int nn = 0; nn < 2; ++nn) {
      const f32x4 av = nn ? acc1 : acc0;
      int col = n0 + (wv * 2 + nn) * 16 + lr;
      #pragma unroll
      for (int r = 0; r < 4; ++r) {
        int rowl = lh * 4 + r;
        size_t gi = (size_t)(m0 + rowl) * DD + col;
        float raw = av[r] + out[gi];
        float mv = g0v[r] * raw + g1v[r] * x[gi];
        s1[r] += mv; s2[r] += mv * mv;
        mbuf[rowl * DD + col] = (bf16)mv;
      }
    }
  }
  #pragma unroll
  for (int r = 0; r < 4; ++r) {
    #pragma unroll
    for (int off = 1; off < 16; off <<= 1) {
      s1[r] += __shfl_xor(s1[r], off);
      s2[r] += __shfl_xor(s2[r], off);
    }
  }
  if (lr == 0) {
    #pragma unroll
    for (int r = 0; r < 4; ++r) {
      wpart[wv][lh * 4 + r][0] = s1[r];
      wpart[wv][lh * 4 + r][1] = s2[r];
    }
  }
  __syncthreads();
  if (tid < 16) {
    float S1 = wpart[0][tid][0] + wpart[1][tid][0] + wpart[2][tid][0] + wpart[3][tid][0];
    float S2 = wpart[0][tid][1] + wpart[1][tid][1] + wpart[2][tid][1] + wpart[3][tid][1];
    float mu = S1 * (1.f / 768.f);
    float var = S2 * (1.f / 768.f) - mu * mu;
    mu_s[tid] = mu;
    rs_s[tid] = rsqrtf(fmaxf(var, 0.f) + 1e-5f);
  }
  __syncthreads();
  #pragma unroll
  for (int i = 0; i < 12; ++i) {
    int gq = i * 256 + tid;
    int row = gq / 192;
    int c4 = gq - row * 192;
    int col = c4 * 4;
    bf16x4 mv = *(const bf16x4*)&mbuf[row * DD + col];
    float4 gg = *(const float4*)&ln_g[col];
    float4 bb = *(const float4*)&ln_b[col];
    float mu = mu_s[row], rs = rs_s[row];
    float4 y;
    y.x = ((float)mv[0] - mu) * rs * gg.x + bb.x;
    y.y = ((float)mv[1] - mu) * rs * gg.y + bb.y;
    y.z = ((float)mv[2] - mu) * rs * gg.z + bb.z;
    y.w = ((float)mv[3] - mu) * rs * gg.w + bb.w;
    *(float4*)&out[(size_t)(m0 + row) * DD + col] = y;
  }
}

// ---------------------------------------------------------------------------
// fallback kernels (R1 pipeline) — only if ws_size is unexpectedly small
// ---------------------------------------------------------------------------
__global__ __launch_bounds__(256) void k_gemm(
    const float* __restrict__ A1, const bf16* __restrict__ A2,
    const bf16* __restrict__ W, float* __restrict__ C,
    int kt1, int kt2, int lda1, int lda2, int ldb, int ldc) {
  __shared__ __align__(16) bf16 As[128][72];
  __shared__ __align__(16) bf16 Bs[128][72];

  const int tid = threadIdx.x;
  const int lane = tid & 63;
  const int wv = tid >> 6;
  const int wr = wv >> 1, wc = wv & 1;
  const int lr = lane & 15, lh = lane >> 4;
  const int bn0 = blockIdx.x * 128;
  const int bm0 = blockIdx.y * 128;

  f32x4 acc[4][4] = {};
  const int KT = kt1 + kt2;

  for (int kt = 0; kt < KT; ++kt) {
    __syncthreads();
    if (kt < kt1) {
      const float* Ab = A1 + (size_t)bm0 * lda1 + kt * 64;
      #pragma unroll
      for (int it = 0; it < 8; ++it) {
        int c = it * 256 + tid;
        int row = c >> 4, col = (c & 15) << 2;
        float4 v = *(const float4*)(Ab + (size_t)row * lda1 + col);
        bf16x4 h;
        h[0] = (bf16)v.x; h[1] = (bf16)v.y; h[2] = (bf16)v.z; h[3] = (bf16)v.w;
        *(bf16x4*)&As[row][col] = h;
      }
    } else {
      const bf16* Ab = A2 + (size_t)bm0 * lda2 + (kt - kt1) * 64;
      #pragma unroll
      for (int it = 0; it < 8; ++it) {
        int c = it * 256 + tid;
        int row = c >> 4, col = (c & 15) << 2;
        bf16x4 v = *(const bf16x4*)(Ab + (size_t)row * lda2 + col);
        *(bf16x4*)&As[row][col] = v;
      }
    }
    {
      const bf16* Bb = W + (size_t)bn0 * ldb + kt * 64;
      #pragma unroll
      for (int it = 0; it < 8; ++it) {
        int c = it * 256 + tid;
        int row = c >> 4, col = (c & 15) << 2;
        bf16x4 v = *(const bf16x4*)(Bb + (size_t)row * ldb + col);
        *(bf16x4*)&Bs[row][col] = v;
      }
    }
    __syncthreads();
    #pragma unroll
    for (int kk = 0; kk < 2; ++kk) {
      bf16x8 af[4], bfr[4];
      #pragma unroll
      for (int f = 0; f < 4; ++f)
        af[f] = *(const bf16x8*)&As[wr * 64 + f * 16 + lr][kk * 32 + lh * 8];
      #pragma unroll
      for (int f = 0; f < 4; ++f)
        bfr[f] = *(const bf16x8*)&Bs[wc * 64 + f * 16 + lr][kk * 32 + lh * 8];
      #pragma unroll
      for (int fi = 0; fi < 4; ++fi)
        #pragma unroll
        for (int fj = 0; fj < 4; ++fj)
          acc[fi][fj] = __builtin_amdgcn_mfma_f32_16x16x32_bf16(
              af[fi], bfr[fj], acc[fi][fj], 0, 0, 0);
    }
  }
  #pragma unroll
  for (int fi = 0; fi < 4; ++fi)
    #pragma unroll
    for (int fj = 0; fj < 4; ++fj) {
      int row = bm0 + wr * 64 + fi * 16 + lh * 4;
      int col = bn0 + wc * 64 + fj * 16 + lr;
      float* Cp = C + (size_t)row * ldc + col;
      #pragma unroll
      for (int r = 0; r < 4; ++r) Cp[(size_t)r * ldc] = acc[fi][fj][r];
    }
}

__global__ __launch_bounds__(512) void k2_scan(
    const float* __restrict__ Bx, const float* __restrict__ A,
    bf16* __restrict__ states) {
  __shared__ __align__(16) float st[2][SS];
  __shared__ __align__(16) float part[3][SS];
  __shared__ __align__(16) float bxb[2][32 * SS];

  const int tid = threadIdx.x;
  const int s = tid & 127;
  const int q = tid >> 7;
  const int b = blockIdx.x;

  float areg[32];
  {
    const float* Ar = A + s * SS + q * 32;
    #pragma unroll
    for (int j = 0; j < 8; ++j) {
      float4 v = *(const float4*)(Ar + j * 4);
      areg[j * 4 + 0] = v.x; areg[j * 4 + 1] = v.y;
      areg[j * 4 + 2] = v.z; areg[j * 4 + 3] = v.w;
    }
  }
  if (tid < SS) st[0][tid] = 0.f;

  const float* Bxb = Bx + (size_t)b * TT * SS;
  {
    float4 c0 = *(const float4*)(Bxb + tid * 4);
    float4 c1 = *(const float4*)(Bxb + 2048 + tid * 4);
    *(float4*)&bxb[0][tid * 4] = c0;
    *(float4*)&bxb[0][2048 + tid * 4] = c1;
  }
  float4 n0 = *(const float4*)(Bxb + 4096 + tid * 4);
  float4 n1 = *(const float4*)(Bxb + 4096 + 2048 + tid * 4);
  __syncthreads();

  bf16* so = states + (size_t)b * TT * SS;
  int p = 0, cur = 0;
  for (int ch = 0; ch < 8; ++ch) {
    #pragma unroll 1
    for (int t2 = 0; t2 < 32; ++t2) {
      const float* stp = st[p];
      float a0 = 0.f, a1 = 0.f, a2 = 0.f, a3 = 0.f;
      #pragma unroll
      for (int j = 0; j < 32; j += 4) {
        float4 sv = *(const float4*)(stp + (q << 5) + j);
        a0 += areg[j]     * sv.x;
        a1 += areg[j + 1] * sv.y;
        a2 += areg[j + 2] * sv.z;
        a3 += areg[j + 3] * sv.w;
      }
      float partial = (a0 + a1) + (a2 + a3);
      if (q) part[q - 1][s] = partial;
      __syncthreads();
      if (q == 0) {
        float tot = partial + part[0][s] + part[1][s] + part[2][s]
                  + bxb[cur][t2 * SS + s];
        tot = fminf(10.f, fmaxf(-10.f, tot));
        st[p ^ 1][s] = tot;
        so[(size_t)(ch * 32 + t2) * SS + s] = (bf16)tot;
      }
      __syncthreads();
      p ^= 1;
    }
    if (ch < 7) {
      *(float4*)&bxb[cur ^ 1][tid * 4] = n0;
      *(float4*)&bxb[cur ^ 1][2048 + tid * 4] = n1;
      if (ch < 6) {
        n0 = *(const float4*)(Bxb + (ch + 2) * 4096 + tid * 4);
        n1 = *(const float4*)(Bxb + (ch + 2) * 4096 + 2048 + tid * 4);
      }
      __syncthreads();
      cur ^= 1;
    }
  }
}

__global__ __launch_bounds__(256) void k4_epilogue(
    float* __restrict__ out, const float* __restrict__ x,
    const float* __restrict__ gate_w, const float* __restrict__ gate_b,
    const float* __restrict__ ln_g, const float* __restrict__ ln_b) {
  const int lane = threadIdx.x & 63;
  const int w = threadIdx.x >> 6;
  const int r = blockIdx.x * 4 + w;

  float4* orow = (float4*)(out + (size_t)r * DD);
  const float4* xrow = (const float4*)(x + (size_t)r * DD);
  const float4* g0w = (const float4*)gate_w;
  const float4* g1w = (const float4*)(gate_w + DD);

  float4 o[3], xv[3];
  float d = 0.f;
  #pragma unroll
  for (int i = 0; i < 3; ++i) {
    int c = i * 64 + lane;
    o[i] = orow[c];
    xv[i] = xrow[c];
    float4 w0 = g0w[c], w1 = g1w[c];
    d += xv[i].x * (w0.x - w1.x) + xv[i].y * (w0.y - w1.y)
       + xv[i].z * (w0.z - w1.z) + xv[i].w * (w0.w - w1.w);
  }
  #pragma unroll
  for (int off = 32; off > 0; off >>= 1) d += __shfl_xor(d, off);
  d += gate_b[0] - gate_b[1];
  float g0 = 1.f / (1.f + expf(-d));
  float g1 = 1.f - g0;

  float4 m[3];
  float s1 = 0.f, s2 = 0.f;
  #pragma unroll
  for (int i = 0; i < 3; ++i) {
    m[i].x = g0 * o[i].x + g1 * xv[i].x;
    m[i].y = g0 * o[i].y + g1 * xv[i].y;
    m[i].z = g0 * o[i].z + g1 * xv[i].z;
    m[i].w = g0 * o[i].w + g1 * xv[i].w;
    s1 += (m[i].x + m[i].y) + (m[i].z + m[i].w);
    s2 += (m[i].x * m[i].x + m[i].y * m[i].y)
        + (m[i].z * m[i].z + m[i].w * m[i].w);
  }
  #pragma unroll
  for (int off = 32; off > 0; off >>= 1) {
    s1 += __shfl_xor(s1, off);
    s2 += __shfl_xor(s2, off);
  }
  float mu = s1 * (1.f / 768.f);
  float var = s2 * (1.f / 768.f) - mu * mu;
  float rs = rsqrtf(var + 1e-5f);

  #pragma unroll
  for (int i = 0; i < 3; ++i) {
    int c = i * 64 + lane;
    float4 gg = ((const float4*)ln_g)[c];
    float4 bb = ((const float4*)ln_b)[c];
    float4 y;
    y.x = (m[i].x - mu) * rs * gg.x + bb.x;
    y.y = (m[i].y - mu) * rs * gg.y + bb.y;
    y.z = (m[i].z - mu) * rs * gg.z + bb.z;
    y.w = (m[i].w - mu) * rs * gg.w + bb.w;
    orow[c] = y;
  }
}

// ---------------------------------------------------------------------------
extern "C" void kernel_launch(void* const* d_in, const int* in_sizes, int n_in,
                              void* d_out, int out_size, void* d_ws, size_t ws_size,
                              hipStream_t stream) {
  const float* x   = (const float*)d_in[0];
  const float* A   = (const float*)d_in[1];
  const float* B_w = (const float*)d_in[2];
  const float* C_w = (const float*)d_in[3];
  const float* D_w = (const float*)d_in[4];
  const float* gw  = (const float*)d_in[5];
  const float* gb  = (const float*)d_in[6];
  const float* lng = (const float*)d_in[7];
  const float* lnb = (const float*)d_in[8];
  float* out = (float*)d_out;

  // ws: W0 | W1 | SB (Bx -> states, in place) | xb | glog(fp32)
  bf16* W0 = (bf16*)d_ws;
  bf16* W1 = W0 + SS * DD;
  bf16* SB = W1 + DD * KW1;
  bf16* xb = SB + (size_t)MM * SS;
  float* glog = (float*)(xb + (size_t)MM * DD);
  const size_t base_bf16 =
      2ull * (SS * DD + DD * KW1 + (size_t)MM * SS + (size_t)MM * DD);
  const size_t ws_need_full = base_bf16 + 4ull * MM;
  const size_t ws_need_min = 2ull * (SS * DD + DD * KW1 + (size_t)MM * SS);

  k0_convert<<<dim3(3072), dim3(256), 0, stream>>>(B_w, D_w, C_w, W0, W1);

  if (ws_size >= ws_need_full) {
    // xb + gate logits in one pass
    k0x_gate<<<dim3(8192), dim3(256), 0, stream>>>(x, xb, gw, gb, glog);
    // SB = Bx (bf16) = xb @ B_w^T
    kg<1><<<dim3(1, 256), dim3(256), 0, stream>>>(
        xb, nullptr, W0, SB, 12, 0, DD, 0, DD, SS, 1);
    // scan (128 blocks, 512t, in-place SB) || out = xb @ D_w^T (768 blocks)
    k_fused<<<dim3(128 + 768), dim3(512), 0, stream>>>(xb, W1, out, SB, A);
    // fused tail: out = LN(g0*(out + states@C_w^T) + g1*x)
    kT<<<dim3(2048), dim3(256), 0, stream>>>(
        SB, W1 + DD, out, x, glog, lng, lnb);
  } else if (ws_size >= ws_need_min) {
    // fallback (R1 pipeline): fp32 Bx in tail of d_out
    float* Bx = out + ((size_t)MM * DD - (size_t)MM * SS);
    bf16* states = SB;
    k_gemm<<<dim3(1, 256), dim3(256), 0, stream>>>(
        x, nullptr, W0, Bx, 12, 0, DD, 0, DD, SS);
    k2_scan<<<dim3(128), dim3(512), 0, stream>>>(Bx, A, states);
    k_gemm<<<dim3(6, 256), dim3(256), 0, stream>>>(
        x, states, W1, out, 12, 2, DD, SS, KW1, DD);
    k4_epilogue<<<dim3(8192), dim3(256), 0, stream>>>(out, x, gw, gb, lng, lnb);
  }
}